// Round 1
// 801.482 us; speedup vs baseline: 1.1436x; 1.1436x over previous
//
#include <hip/hip_runtime.h>

#define NUM_GRAPHS 4096
#define DV 32            // float4 chunks per 128-float row
#define EPS 1e-5f
#define RK 36            // cached float4 per thread: covers cnt <= 288 without re-read

typedef float f32x4 __attribute__((ext_vector_type(4)));

// ---------------------------------------------------------------------------
// Helper: segment boundaries. starts[g] = first row of graph g, starts[G] = n.
// batch is sorted, so each thread marks the boundary it sits on.
// ---------------------------------------------------------------------------
__global__ __launch_bounds__(256) void boundaries_kernel(
    const int* __restrict__ batch, int* __restrict__ starts, int n)
{
    int i = blockIdx.x * blockDim.x + threadIdx.x;
    if (i >= n) return;
    int b0 = batch[i];
    int b1 = (i + 1 < n) ? batch[i + 1] : NUM_GRAPHS;
    if (i == 0) {
        for (int g = 0; g <= b0; ++g) starts[g] = 0;
    }
    for (int g = b0 + 1; g <= b1; ++g) starts[g] = i + 1;
}

// ---------------------------------------------------------------------------
// Main kernel: one block per graph.
//   phase 1: guarded, fully-unrolled nontemporal loads into a register cache
//            (36-deep MLP per wave) + sum/sumsq accumulate
//   reduce:  cross-wave via LDS (t<32 finishes)
//   phase 2: out = reg*A + C, nontemporal stores — NO re-read of x
// Streaming-tail fallback keeps correctness for cnt > 8*RK.
// starts==nullptr falls back to per-block binary search (tiny-ws safety).
// ---------------------------------------------------------------------------
__global__ __launch_bounds__(256, 2) void graphnorm_kernel(
    const float* __restrict__ x,
    const int*   __restrict__ batch,
    const int*   __restrict__ starts,
    const float* __restrict__ weight,
    const float* __restrict__ bias,
    float*       __restrict__ out,
    int n_nodes)
{
    const int g = blockIdx.x;
    const int t = threadIdx.x;
    const int c = t & 31;     // float4 column within the row
    const int r = t >> 5;     // row-group 0..7

    int start, end;
    if (starts != nullptr) {
        start = starts[g];
        end   = starts[g + 1];
    } else {
        int lo = 0, hi = n_nodes;
        while (lo < hi) { int m = (lo + hi) >> 1; if (batch[m] < g) lo = m + 1; else hi = m; }
        start = lo;
        hi = n_nodes;
        while (lo < hi) { int m = (lo + hi) >> 1; if (batch[m] < g + 1) lo = m + 1; else hi = m; }
        end = lo;
    }
    const int cnt = end - start;
    if (cnt == 0) return;

    __shared__ f32x4 red_s[256];
    __shared__ f32x4 red_q[256];
    __shared__ f32x4 sm_a[32];   // scale  = w * inv_std
    __shared__ f32x4 sm_c[32];   // offset = b - mean * scale

    const f32x4* __restrict__ xr  = (const f32x4*)x   + (size_t)start * DV + c;
    f32x4*       __restrict__ orr = (f32x4*)out       + (size_t)start * DV + c;

    f32x4 reg[RK];
    f32x4 s = {0.f, 0.f, 0.f, 0.f};
    f32x4 q = {0.f, 0.f, 0.f, 0.f};

    // --- phase 1a: issue all cached loads (static indices -> stays in VGPRs) ---
    #pragma unroll
    for (int k = 0; k < RK; ++k) {
        const int i = r + 8 * k;
        if (i < cnt) reg[k] = __builtin_nontemporal_load(xr + (size_t)i * DV);
    }
    // --- phase 1b: accumulate sum / sumsq ---
    #pragma unroll
    for (int k = 0; k < RK; ++k) {
        const int i = r + 8 * k;
        if (i < cnt) {
            f32x4 v = reg[k];
            s += v;
            q += v * v;
        }
    }
    // --- streaming tail for cnt > 8*RK (rare; cached normally so phase 2 re-read hits) ---
    for (int i = r + 8 * RK; i < cnt; i += 8) {
        f32x4 v = xr[(size_t)i * DV];
        s += v;
        q += v * v;
    }

    red_s[t] = s;
    red_q[t] = q;
    __syncthreads();

    if (t < 32) {
        f32x4 S = red_s[t], Q = red_q[t];
        #pragma unroll
        for (int j = 1; j < 8; ++j) {
            S += red_s[t + 32 * j];
            Q += red_q[t + 32 * j];
        }
        f32x4 mean = {0.f, 0.f, 0.f, 0.f};
        f32x4 var  = {1.f, 1.f, 1.f, 1.f};
        if (cnt > 1) {
            const float ic = 1.0f / (float)cnt;
            mean = S * ic;
            var.x = fmaf(-mean.x, mean.x, Q.x * ic);
            var.y = fmaf(-mean.y, mean.y, Q.y * ic);
            var.z = fmaf(-mean.z, mean.z, Q.z * ic);
            var.w = fmaf(-mean.w, mean.w, Q.w * ic);
        }
        f32x4 inv;
        inv.x = rsqrtf(var.x + EPS);
        inv.y = rsqrtf(var.y + EPS);
        inv.z = rsqrtf(var.z + EPS);
        inv.w = rsqrtf(var.w + EPS);

        f32x4 w4 = ((const f32x4*)weight)[t];
        f32x4 b4 = ((const f32x4*)bias)[t];
        f32x4 A = w4 * inv;
        f32x4 C;
        C.x = fmaf(-mean.x, A.x, b4.x);
        C.y = fmaf(-mean.y, A.y, b4.y);
        C.z = fmaf(-mean.z, A.z, b4.z);
        C.w = fmaf(-mean.w, A.w, b4.w);
        sm_a[t] = A;
        sm_c[t] = C;
    }
    __syncthreads();

    // --- phase 2: out = reg * A + C straight from the register cache ---
    const f32x4 A = sm_a[c];
    const f32x4 C = sm_c[c];
    #pragma unroll
    for (int k = 0; k < RK; ++k) {
        const int i = r + 8 * k;
        if (i < cnt) {
            f32x4 v = reg[k];
            f32x4 o;
            o.x = fmaf(v.x, A.x, C.x);
            o.y = fmaf(v.y, A.y, C.y);
            o.z = fmaf(v.z, A.z, C.z);
            o.w = fmaf(v.w, A.w, C.w);
            __builtin_nontemporal_store(o, orr + (size_t)i * DV);
        }
    }
    for (int i = r + 8 * RK; i < cnt; i += 8) {
        f32x4 v = xr[(size_t)i * DV];
        f32x4 o;
        o.x = fmaf(v.x, A.x, C.x);
        o.y = fmaf(v.y, A.y, C.y);
        o.z = fmaf(v.z, A.z, C.z);
        o.w = fmaf(v.w, A.w, C.w);
        __builtin_nontemporal_store(o, orr + (size_t)i * DV);
    }
}

extern "C" void kernel_launch(void* const* d_in, const int* in_sizes, int n_in,
                              void* d_out, int out_size, void* d_ws, size_t ws_size,
                              hipStream_t stream) {
    const float* x      = (const float*)d_in[0];
    const int*   batch  = (const int*)d_in[1];
    const float* weight = (const float*)d_in[2];
    const float* bias   = (const float*)d_in[3];
    float*       out    = (float*)d_out;
    const int n_nodes = in_sizes[1];

    int* starts = nullptr;
    if (d_ws != nullptr && ws_size >= (size_t)(NUM_GRAPHS + 1) * sizeof(int)) {
        starts = (int*)d_ws;
        int nb = (n_nodes + 255) / 256;
        boundaries_kernel<<<nb, 256, 0, stream>>>(batch, starts, n_nodes);
    }
    graphnorm_kernel<<<NUM_GRAPHS, 256, 0, stream>>>(
        x, batch, starts, weight, bias, out, n_nodes);
}